// Round 1
// baseline (939.800 us; speedup 1.0000x reference)
//
#include <hip/hip_runtime.h>
#include <math.h>

#define S_LEN   8192
#define DMODEL  1024
#define B_SZ    2
#define NH      16
#define HD      64
#define KSEL    1024
#define CHUNKQ  256
#define WINDOW  512
#define NEG_BIG -1000000000.0f
#define RMSEPS  1.1920929e-07f

// ---------------------------------------------------------------- zero output
__global__ void k_zero(float4* __restrict__ o, int n4) {
    int i = blockIdx.x * blockDim.x + threadIdx.x;
    if (i < n4) o[i] = make_float4(0.f, 0.f, 0.f, 0.f);
}

// ---------------------------------------------------------- routing scores
// scores[b, t] = mean_d | ss(x[b,t+1,d]) - cheby[b,t,d] |  for t in [0, S-1)
__global__ __launch_bounds__(256) void k_scores(const float* __restrict__ x,
                                                const float* __restrict__ cheby,
                                                float* __restrict__ scores) {
    int lin = blockIdx.x;
    int b = lin / (S_LEN - 1);
    int t = lin % (S_LEN - 1);
    const float4* xr = (const float4*)(x + ((size_t)b * S_LEN + t + 1) * DMODEL);
    const float4* cr = (const float4*)(cheby + ((size_t)b * S_LEN + t) * DMODEL);
    float4 xv = xr[threadIdx.x];
    float4 cv = cr[threadIdx.x];
    double acc = 0.0;
    {
        float vs[4] = {xv.x, xv.y, xv.z, xv.w};
        float cs[4] = {cv.x, cv.y, cv.z, cv.w};
#pragma unroll
        for (int j = 0; j < 4; ++j) {
            float ax = fmaxf(fabsf(vs[j]), 1e-7f);
            float ss = copysignf(1.0f - 1.0f / (1.0f + ax), vs[j]);
            acc += (double)fabsf(ss - cs[j]);
        }
    }
    int lane = threadIdx.x & 63, wid = threadIdx.x >> 6;
#pragma unroll
    for (int o = 32; o; o >>= 1) acc += __shfl_down(acc, o);
    __shared__ double wred[4];
    if (lane == 0) wred[wid] = acc;
    __syncthreads();
    if (threadIdx.x == 0) {
        double tot = wred[0] + wred[1] + wred[2] + wred[3];
        scores[(size_t)b * S_LEN + t] = (float)(tot * (1.0 / 1024.0));
    }
}

// ------------------------------------------------------------------- top-K
// One block per batch. Finds K-th largest via radix select on float bits
// (scores >= 0 so uint order == float order), tie-break lower-index-first,
// emits indices sorted ascending via prefix-sum compaction.
__global__ __launch_bounds__(1024) void k_topk(const float* __restrict__ scores,
                                               int* __restrict__ indices) {
    const int b = blockIdx.x;
    const int tid = threadIdx.x;
    const int lane = tid & 63, wid = tid >> 6;
    __shared__ unsigned vals[S_LEN];
    __shared__ unsigned hist[256];
    __shared__ unsigned sfx[256];
    __shared__ unsigned wsum[16];
    __shared__ unsigned bcast[2];
    __shared__ float fred[16];

    // load scores[0..S-2]; compute their max -> vals[S-1] (reference's last entry)
    float mx = -1e30f;
    for (int i = tid; i < S_LEN - 1; i += 1024) {
        float v = scores[(size_t)b * S_LEN + i];
        vals[i] = __float_as_uint(v);
        mx = fmaxf(mx, v);
    }
#pragma unroll
    for (int o = 32; o; o >>= 1) mx = fmaxf(mx, __shfl_down(mx, o));
    if (lane == 0) fred[wid] = mx;
    __syncthreads();
    if (tid == 0) {
        float m2 = fred[0];
        for (int w = 1; w < 16; ++w) m2 = fmaxf(m2, fred[w]);
        vals[S_LEN - 1] = __float_as_uint(m2);
    }
    __syncthreads();

    // radix select: find bit pattern T of the K-th largest
    unsigned prefix = 0, remaining = KSEL;
    for (int p = 3; p >= 0; --p) {
        unsigned hm = (p == 3) ? 0u : (0xFFFFFFFFu << ((p + 1) * 8));
        if (tid < 256) hist[tid] = 0u;
        __syncthreads();
        for (int i = tid; i < S_LEN; i += 1024) {
            unsigned v = vals[i];
            if ((v & hm) == (prefix & hm))
                atomicAdd(&hist[(v >> (p * 8)) & 255u], 1u);
        }
        __syncthreads();
        if (tid < 256) sfx[tid] = hist[tid];
        __syncthreads();
        for (int off = 1; off < 256; off <<= 1) {   // inclusive suffix sums
            unsigned add = 0;
            if (tid < 256 && tid + off < 256) add = sfx[tid + off];
            __syncthreads();
            if (tid < 256) sfx[tid] += add;
            __syncthreads();
        }
        if (tid < 256) {
            unsigned Sb  = sfx[tid];
            unsigned Sb1 = (tid < 255) ? sfx[tid + 1] : 0u;
            if (Sb >= remaining && Sb1 < remaining) { bcast[0] = (unsigned)tid; bcast[1] = Sb1; }
        }
        __syncthreads();
        prefix |= bcast[0] << (p * 8);
        remaining -= bcast[1];
        __syncthreads();
    }
    const unsigned T = prefix;
    const unsigned need = remaining;   // how many == T to take (ascending index)

    // each thread owns 8 consecutive positions
    const int p0 = tid * 8;
    unsigned vloc[8];
#pragma unroll
    for (int j = 0; j < 8; ++j) vloc[j] = vals[p0 + j];

    // pass 1: rank among equals (ascending index)
    unsigned eqpre[8]; unsigned myeq = 0;
#pragma unroll
    for (int j = 0; j < 8; ++j) { eqpre[j] = myeq; myeq += (vloc[j] == T) ? 1u : 0u; }
    // block exclusive scan of myeq
    unsigned inc = myeq;
#pragma unroll
    for (int o = 1; o < 64; o <<= 1) { unsigned u = __shfl_up(inc, o); if (lane >= o) inc += u; }
    if (lane == 63) wsum[wid] = inc;
    __syncthreads();
    if (wid == 0) {
        unsigned w = (lane < 16) ? wsum[lane] : 0u;
        unsigned winc = w;
#pragma unroll
        for (int o = 1; o < 16; o <<= 1) { unsigned u = __shfl_up(winc, o); if (lane >= o) winc += u; }
        if (lane < 16) wsum[lane] = winc - w;
    }
    __syncthreads();
    const unsigned eqbase = wsum[wid] + inc - myeq;
    __syncthreads();

    // pass 2: final selection flags + compaction offsets
    unsigned fpre[8]; unsigned myf = 0; unsigned fl = 0;
#pragma unroll
    for (int j = 0; j < 8; ++j) {
        bool f = (vloc[j] > T) || ((vloc[j] == T) && (eqbase + eqpre[j] < need));
        fl |= (f ? 1u : 0u) << j;
        fpre[j] = myf;
        myf += f ? 1u : 0u;
    }
    unsigned inc2 = myf;
#pragma unroll
    for (int o = 1; o < 64; o <<= 1) { unsigned u = __shfl_up(inc2, o); if (lane >= o) inc2 += u; }
    if (lane == 63) wsum[wid] = inc2;
    __syncthreads();
    if (wid == 0) {
        unsigned w = (lane < 16) ? wsum[lane] : 0u;
        unsigned winc = w;
#pragma unroll
        for (int o = 1; o < 16; o <<= 1) { unsigned u = __shfl_up(winc, o); if (lane >= o) winc += u; }
        if (lane < 16) wsum[lane] = winc - w;
    }
    __syncthreads();
    const unsigned fbase = wsum[wid] + inc2 - myf;
#pragma unroll
    for (int j = 0; j < 8; ++j)
        if ((fl >> j) & 1u)
            indices[b * KSEL + fbase + fpre[j]] = p0 + j;
}

// ------------------------------------------------------------- RoPE tables
__global__ void k_rope_tab(const int* __restrict__ idxs,
                           float* __restrict__ rcos, float* __restrict__ rsin) {
    int g = blockIdx.x * blockDim.x + threadIdx.x;
    if (g >= B_SZ * KSEL * 32) return;
    int i = g & 31, bm = g >> 5;
    int b = bm >> 10, m = bm & 1023;
    float pos = (float)idxs[b * KSEL + m];
    // theta_i = 10000^(-2i/64) computed in double, rounded to fp32, then fp32 multiply
    double th = exp2(-(double)i * (13.287712379549449 / 32.0));
    float freq = pos * (float)th;
    float s, c;
    sincosf(freq, &s, &c);
    rcos[g] = c;
    rsin[g] = s;
}

__global__ __launch_bounds__(256) void k_rope_apply(float* __restrict__ qkv,
                                                    const float* __restrict__ rcos,
                                                    const float* __restrict__ rsin) {
    int bm = blockIdx.x;
    float* row = qkv + (size_t)bm * 4096;
    for (int p = threadIdx.x; p < 1536; p += 256) {   // 3 streams x 16 heads x 32 pairs
        int s = p / 512, r = p % 512;
        int h = r >> 5, i = r & 31;
        float c = rcos[bm * 32 + i], sn = rsin[bm * 32 + i];
        int off = s * 1024 + h * 64 + 2 * i;
        float x1 = row[off], x2 = row[off + 1];
        row[off]     = x1 * c - x2 * sn;
        row[off + 1] = x1 * sn + x2 * c;
    }
}

// -------------------------------------------------------- QKV GEMM (gathered)
// qkv[r, n] = sum_k x[row(r), k] * Wq[n, k];  r in [0, B*K), n in [0, 4096)
__global__ __launch_bounds__(256) void k_qkv(const float* __restrict__ x,
                                             const float* __restrict__ Wq,
                                             const int* __restrict__ idxs,
                                             float* __restrict__ qkv) {
    __shared__ float As[16][128];
    __shared__ float Bs[16][128];
    __shared__ int rows[128];
    const int tid = threadIdx.x;
    const int bn = blockIdx.x, bm = blockIdx.y;
    if (tid < 128) {
        int r = bm * 128 + tid;
        int b = r >> 10, m = r & 1023;
        rows[tid] = b * S_LEN + idxs[b * KSEL + m];
    }
    const int tx = tid & 15, ty = tid >> 4;
    const int lm = tid >> 1, lk = (tid & 1) * 8;
    float acc[8][8];
#pragma unroll
    for (int i = 0; i < 8; ++i)
#pragma unroll
        for (int j = 0; j < 8; ++j) acc[i][j] = 0.f;
    __syncthreads();
    const size_t arow = (size_t)rows[lm] * DMODEL;
    const float* bbase = Wq + (size_t)(bn * 128 + lm) * DMODEL + lk;
    for (int k0 = 0; k0 < DMODEL; k0 += 16) {
        const float* asrc = x + arow + k0 + lk;
        float4 a0 = *(const float4*)asrc;
        float4 a1 = *(const float4*)(asrc + 4);
        float4 b0 = *(const float4*)(bbase + k0);
        float4 b1 = *(const float4*)(bbase + k0 + 4);
        __syncthreads();
        As[lk + 0][lm] = a0.x; As[lk + 1][lm] = a0.y; As[lk + 2][lm] = a0.z; As[lk + 3][lm] = a0.w;
        As[lk + 4][lm] = a1.x; As[lk + 5][lm] = a1.y; As[lk + 6][lm] = a1.z; As[lk + 7][lm] = a1.w;
        Bs[lk + 0][lm] = b0.x; Bs[lk + 1][lm] = b0.y; Bs[lk + 2][lm] = b0.z; Bs[lk + 3][lm] = b0.w;
        Bs[lk + 4][lm] = b1.x; Bs[lk + 5][lm] = b1.y; Bs[lk + 6][lm] = b1.z; Bs[lk + 7][lm] = b1.w;
        __syncthreads();
#pragma unroll
        for (int k = 0; k < 16; ++k) {
            float a[8], bb[8];
            *(float4*)&a[0]  = *(const float4*)&As[k][ty * 4];
            *(float4*)&a[4]  = *(const float4*)&As[k][64 + ty * 4];
            *(float4*)&bb[0] = *(const float4*)&Bs[k][tx * 4];
            *(float4*)&bb[4] = *(const float4*)&Bs[k][64 + tx * 4];
#pragma unroll
            for (int i = 0; i < 8; ++i)
#pragma unroll
                for (int j = 0; j < 8; ++j) acc[i][j] += a[i] * bb[j];
        }
    }
#pragma unroll
    for (int i = 0; i < 8; ++i) {
        int r = bm * 128 + ((i < 4) ? (ty * 4 + i) : (60 + ty * 4 + i));
        float* crow = qkv + (size_t)r * 4096 + bn * 128;
        *(float4*)&crow[tx * 4]      = make_float4(acc[i][0], acc[i][1], acc[i][2], acc[i][3]);
        *(float4*)&crow[64 + tx * 4] = make_float4(acc[i][4], acc[i][5], acc[i][6], acc[i][7]);
    }
}

// ------------------------------------------------------------- attention
// grid: 256 = b(2) x h(16) x chunk(4) x stream(2); 256 threads = 1 query each
__global__ __launch_bounds__(256) void k_attn(const float* __restrict__ qkv,
                                              const int* __restrict__ idxs,
                                              float* __restrict__ o1,
                                              float* __restrict__ o2) {
    const int lin = blockIdx.x;
    const int s = lin & 1, c = (lin >> 1) & 3, h = (lin >> 3) & 15, b = lin >> 7;
    const int q0 = c * CHUNKQ;
    const int k0 = (q0 >= CHUNKQ) ? (q0 - CHUNKQ) : 0;
    const int klen = q0 + CHUNKQ - k0;          // 256 or 512
    const int tid = threadIdx.x;

    __shared__ float4 Kt[64 * 16];
    __shared__ float4 Vt[64 * 16];
    __shared__ int pk[512];
    for (int i = tid; i < klen; i += 256) pk[i] = idxs[b * KSEL + k0 + i];
    const int pq = idxs[b * KSEL + q0 + tid];

    const float* qrow = qkv + ((size_t)(b * KSEL + q0 + tid) * 4096) + s * 1024 + h * 64;
    float4 qv[16];
#pragma unroll
    for (int i = 0; i < 16; ++i) qv[i] = ((const float4*)qrow)[i];
    float4 accv[16];
#pragma unroll
    for (int i = 0; i < 16; ++i) accv[i] = make_float4(0.f, 0.f, 0.f, 0.f);
    float m = -INFINITY, l = 0.f;

    for (int kt = 0; kt < klen; kt += 64) {
        __syncthreads();
        {
            int kk = tid >> 2, qq = tid & 3;
            const size_t krow = (size_t)(b * KSEL + k0 + kt + kk) * 4096;
            const float4* ksrc = (const float4*)(qkv + krow + 2048 + h * 64 + qq * 16);
            const float4* vsrc = (const float4*)(qkv + krow + 3072 + h * 64 + qq * 16);
#pragma unroll
            for (int j = 0; j < 4; ++j) {
                Kt[kk * 16 + qq * 4 + j] = ksrc[j];
                Vt[kk * 16 + qq * 4 + j] = vsrc[j];
            }
        }
        __syncthreads();
        for (int j = 0; j < 64; ++j) {
            float sc = 0.f;
#pragma unroll
            for (int i = 0; i < 16; ++i) {
                float4 kv = Kt[j * 16 + i];
                sc += qv[i].x * kv.x + qv[i].y * kv.y + qv[i].z * kv.z + qv[i].w * kv.w;
            }
            sc *= 0.125f;
            int pkk = pk[kt + j];
            bool ok = (pkk <= pq) && (pq - pkk < WINDOW);
            sc = ok ? sc : NEG_BIG;
            if (sc > m) {
                float sf = expf(m - sc);   // m may be -inf: expf(-inf)=0 zeroes history
                l *= sf;
#pragma unroll
                for (int i = 0; i < 16; ++i) {
                    accv[i].x *= sf; accv[i].y *= sf; accv[i].z *= sf; accv[i].w *= sf;
                }
                m = sc;
            }
            float p = expf(sc - m);
            l += p;
#pragma unroll
            for (int i = 0; i < 16; ++i) {
                float4 vv = Vt[j * 16 + i];
                accv[i].x += p * vv.x; accv[i].y += p * vv.y;
                accv[i].z += p * vv.z; accv[i].w += p * vv.w;
            }
        }
    }
    const float inv = 1.0f / l;
    float* dst = (s ? o2 : o1) + ((size_t)(b * KSEL + q0 + tid) * 1024) + h * 64;
#pragma unroll
    for (int i = 0; i < 16; ++i) {
        float4 ov = accv[i];
        ((float4*)dst)[i] = make_float4(ov.x * inv, ov.y * inv, ov.z * inv, ov.w * inv);
    }
}

// ------------------------------------- diff + output GEMM: y = (o1 - lam*o2) @ Wo^T
__global__ __launch_bounds__(256) void k_ogemm(const float* __restrict__ o1,
                                               const float* __restrict__ o2,
                                               const float* __restrict__ Wo,
                                               const float* __restrict__ dll,
                                               float* __restrict__ y) {
    __shared__ float As[16][128];
    __shared__ float Bs[16][128];
    __shared__ float lams[16];
    const int tid = threadIdx.x;
    const int bn = blockIdx.x, bm = blockIdx.y;
    if (tid < 16) lams[tid] = 1.0f / (1.0f + expf(-dll[tid]));
    const int tx = tid & 15, ty = tid >> 4;
    const int lm = tid >> 1, lk = (tid & 1) * 8;
    float acc[8][8];
#pragma unroll
    for (int i = 0; i < 8; ++i)
#pragma unroll
        for (int j = 0; j < 8; ++j) acc[i][j] = 0.f;
    __syncthreads();
    const int r = bm * 128 + lm;
    const float* s1base = o1 + (size_t)r * 1024 + lk;
    const float* s2base = o2 + (size_t)r * 1024 + lk;
    const float* bbase = Wo + (size_t)(bn * 128 + lm) * 1024 + lk;
    for (int k0 = 0; k0 < 1024; k0 += 16) {
        float lam = lams[(k0 + lk) >> 6];
        float4 p0 = *(const float4*)(s1base + k0);
        float4 p1 = *(const float4*)(s1base + k0 + 4);
        float4 q0 = *(const float4*)(s2base + k0);
        float4 q1 = *(const float4*)(s2base + k0 + 4);
        float4 b0 = *(const float4*)(bbase + k0);
        float4 b1 = *(const float4*)(bbase + k0 + 4);
        __syncthreads();
        As[lk + 0][lm] = p0.x - lam * q0.x; As[lk + 1][lm] = p0.y - lam * q0.y;
        As[lk + 2][lm] = p0.z - lam * q0.z; As[lk + 3][lm] = p0.w - lam * q0.w;
        As[lk + 4][lm] = p1.x - lam * q1.x; As[lk + 5][lm] = p1.y - lam * q1.y;
        As[lk + 6][lm] = p1.z - lam * q1.z; As[lk + 7][lm] = p1.w - lam * q1.w;
        Bs[lk + 0][lm] = b0.x; Bs[lk + 1][lm] = b0.y; Bs[lk + 2][lm] = b0.z; Bs[lk + 3][lm] = b0.w;
        Bs[lk + 4][lm] = b1.x; Bs[lk + 5][lm] = b1.y; Bs[lk + 6][lm] = b1.z; Bs[lk + 7][lm] = b1.w;
        __syncthreads();
#pragma unroll
        for (int k = 0; k < 16; ++k) {
            float a[8], bb[8];
            *(float4*)&a[0]  = *(const float4*)&As[k][ty * 4];
            *(float4*)&a[4]  = *(const float4*)&As[k][64 + ty * 4];
            *(float4*)&bb[0] = *(const float4*)&Bs[k][tx * 4];
            *(float4*)&bb[4] = *(const float4*)&Bs[k][64 + tx * 4];
#pragma unroll
            for (int i = 0; i < 8; ++i)
#pragma unroll
                for (int j = 0; j < 8; ++j) acc[i][j] += a[i] * bb[j];
        }
    }
#pragma unroll
    for (int i = 0; i < 8; ++i) {
        int r2 = bm * 128 + ((i < 4) ? (ty * 4 + i) : (60 + ty * 4 + i));
        float* crow = y + (size_t)r2 * 1024 + bn * 128;
        *(float4*)&crow[tx * 4]      = make_float4(acc[i][0], acc[i][1], acc[i][2], acc[i][3]);
        *(float4*)&crow[64 + tx * 4] = make_float4(acc[i][4], acc[i][5], acc[i][6], acc[i][7]);
    }
}

// -------------------------------------------------- RMS norm + scatter rows
__global__ __launch_bounds__(256) void k_rms(const float* __restrict__ y,
                                             const int* __restrict__ idxs,
                                             const float* __restrict__ w,
                                             float* __restrict__ out) {
    const int r = blockIdx.x;
    const int b = r >> 10, m = r & 1023;
    const float4 v = ((const float4*)(y + (size_t)r * 1024))[threadIdx.x];
    double ss = (double)v.x * v.x + (double)v.y * v.y + (double)v.z * v.z + (double)v.w * v.w;
    int lane = threadIdx.x & 63, wid = threadIdx.x >> 6;
#pragma unroll
    for (int o = 32; o; o >>= 1) ss += __shfl_down(ss, o);
    __shared__ double wr[4];
    if (lane == 0) wr[wid] = ss;
    __syncthreads();
    double tot = wr[0] + wr[1] + wr[2] + wr[3];
    float sc = 1.0f / sqrtf((float)(tot * (1.0 / 1024.0)) + RMSEPS);
    float4 wv = ((const float4*)w)[threadIdx.x];
    int row = idxs[b * KSEL + m];
    float4 o4 = make_float4((v.x * sc) * wv.x, (v.y * sc) * wv.y,
                            (v.z * sc) * wv.z, (v.w * sc) * wv.w);
    ((float4*)(out + ((size_t)b * S_LEN + row) * 1024))[threadIdx.x] = o4;
}

// ----------------------------------------------------------------- launcher
extern "C" void kernel_launch(void* const* d_in, const int* in_sizes, int n_in,
                              void* d_out, int out_size, void* d_ws, size_t ws_size,
                              hipStream_t stream) {
    (void)in_sizes; (void)n_in; (void)out_size; (void)ws_size;
    const float* x     = (const float*)d_in[0];
    const float* cheby = (const float*)d_in[1];
    const float* Wqkv  = (const float*)d_in[2];
    const float* Wo    = (const float*)d_in[3];
    const float* rmsw  = (const float*)d_in[4];
    const float* dll   = (const float*)d_in[5];
    float* out = (float*)d_out;

    float* ws = (float*)d_ws;
    float* scores = ws;                                   // 16384
    int*   indices = (int*)(ws + 16384);                  // 2048 ints
    float* rcos = ws + 16384 + 2048;                      // 65536
    float* rsin = rcos + 65536;                           // 65536
    float* qkv  = rsin + 65536;                           // 8388608 (B*K*4096)
    float* o1   = qkv + 8388608;                          // 2097152
    float* o2   = o1 + 2097152;                           // 2097152
    float* yb   = o2 + 2097152;                           // 2097152
    // total ~59.3 MB of workspace

    k_zero<<<16384, 256, 0, stream>>>((float4*)out, (B_SZ * S_LEN * DMODEL) / 4);
    k_scores<<<B_SZ * (S_LEN - 1), 256, 0, stream>>>(x, cheby, scores);
    k_topk<<<B_SZ, 1024, 0, stream>>>(scores, indices);
    k_rope_tab<<<(B_SZ * KSEL * 32 + 255) / 256, 256, 0, stream>>>(indices, rcos, rsin);
    k_qkv<<<dim3(32, 16), 256, 0, stream>>>(x, Wqkv, indices, qkv);
    k_rope_apply<<<B_SZ * KSEL, 256, 0, stream>>>(qkv, rcos, rsin);
    k_attn<<<256, 256, 0, stream>>>(qkv, indices, o1, o2);
    k_ogemm<<<dim3(8, 16), 256, 0, stream>>>(o1, o2, Wo, dll, yb);
    k_rms<<<B_SZ * KSEL, 256, 0, stream>>>(yb, indices, rmsw, out);
}

// Round 2
// 791.137 us; speedup vs baseline: 1.1879x; 1.1879x over previous
//
#include <hip/hip_runtime.h>
#include <math.h>

#define S_LEN   8192
#define DMODEL  1024
#define B_SZ    2
#define NH      16
#define HD      64
#define KSEL    1024
#define CHUNKQ  256
#define WINDOW  512
#define NEG_BIG -1000000000.0f
#define RMSEPS  1.1920929e-07f

// ---------------------------------------------------------------- zero output
__global__ void k_zero(float4* __restrict__ o, int n4) {
    int i = blockIdx.x * blockDim.x + threadIdx.x;
    if (i < n4) o[i] = make_float4(0.f, 0.f, 0.f, 0.f);
}

// ---------------------------------------------------------- routing scores
// scores[b, t] = mean_d | ss(x[b,t+1,d]) - cheby[b,t,d] |  for t in [0, S-1)
__global__ __launch_bounds__(256) void k_scores(const float* __restrict__ x,
                                                const float* __restrict__ cheby,
                                                float* __restrict__ scores) {
    int lin = blockIdx.x;
    int b = lin / (S_LEN - 1);
    int t = lin % (S_LEN - 1);
    const float4* xr = (const float4*)(x + ((size_t)b * S_LEN + t + 1) * DMODEL);
    const float4* cr = (const float4*)(cheby + ((size_t)b * S_LEN + t) * DMODEL);
    float4 xv = xr[threadIdx.x];
    float4 cv = cr[threadIdx.x];
    double acc = 0.0;
    {
        float vs[4] = {xv.x, xv.y, xv.z, xv.w};
        float cs[4] = {cv.x, cv.y, cv.z, cv.w};
#pragma unroll
        for (int j = 0; j < 4; ++j) {
            float ax = fmaxf(fabsf(vs[j]), 1e-7f);
            float ss = copysignf(1.0f - 1.0f / (1.0f + ax), vs[j]);
            acc += (double)fabsf(ss - cs[j]);
        }
    }
    int lane = threadIdx.x & 63, wid = threadIdx.x >> 6;
#pragma unroll
    for (int o = 32; o; o >>= 1) acc += __shfl_down(acc, o);
    __shared__ double wred[4];
    if (lane == 0) wred[wid] = acc;
    __syncthreads();
    if (threadIdx.x == 0) {
        double tot = wred[0] + wred[1] + wred[2] + wred[3];
        scores[(size_t)b * S_LEN + t] = (float)(tot * (1.0 / 1024.0));
    }
}

// ------------------------------------------------------------------- top-K
// One block per batch. Finds K-th largest via radix select on float bits
// (scores >= 0 so uint order == float order), tie-break lower-index-first,
// emits indices sorted ascending via prefix-sum compaction.
__global__ __launch_bounds__(1024) void k_topk(const float* __restrict__ scores,
                                               int* __restrict__ indices) {
    const int b = blockIdx.x;
    const int tid = threadIdx.x;
    const int lane = tid & 63, wid = tid >> 6;
    __shared__ unsigned vals[S_LEN];
    __shared__ unsigned hist[256];
    __shared__ unsigned sfx[256];
    __shared__ unsigned wsum[16];
    __shared__ unsigned bcast[2];
    __shared__ float fred[16];

    // load scores[0..S-2]; compute their max -> vals[S-1] (reference's last entry)
    float mx = -1e30f;
    for (int i = tid; i < S_LEN - 1; i += 1024) {
        float v = scores[(size_t)b * S_LEN + i];
        vals[i] = __float_as_uint(v);
        mx = fmaxf(mx, v);
    }
#pragma unroll
    for (int o = 32; o; o >>= 1) mx = fmaxf(mx, __shfl_down(mx, o));
    if (lane == 0) fred[wid] = mx;
    __syncthreads();
    if (tid == 0) {
        float m2 = fred[0];
        for (int w = 1; w < 16; ++w) m2 = fmaxf(m2, fred[w]);
        vals[S_LEN - 1] = __float_as_uint(m2);
    }
    __syncthreads();

    // radix select: find bit pattern T of the K-th largest
    unsigned prefix = 0, remaining = KSEL;
    for (int p = 3; p >= 0; --p) {
        unsigned hm = (p == 3) ? 0u : (0xFFFFFFFFu << ((p + 1) * 8));
        if (tid < 256) hist[tid] = 0u;
        __syncthreads();
        for (int i = tid; i < S_LEN; i += 1024) {
            unsigned v = vals[i];
            if ((v & hm) == (prefix & hm))
                atomicAdd(&hist[(v >> (p * 8)) & 255u], 1u);
        }
        __syncthreads();
        if (tid < 256) sfx[tid] = hist[tid];
        __syncthreads();
        for (int off = 1; off < 256; off <<= 1) {   // inclusive suffix sums
            unsigned add = 0;
            if (tid < 256 && tid + off < 256) add = sfx[tid + off];
            __syncthreads();
            if (tid < 256) sfx[tid] += add;
            __syncthreads();
        }
        if (tid < 256) {
            unsigned Sb  = sfx[tid];
            unsigned Sb1 = (tid < 255) ? sfx[tid + 1] : 0u;
            if (Sb >= remaining && Sb1 < remaining) { bcast[0] = (unsigned)tid; bcast[1] = Sb1; }
        }
        __syncthreads();
        prefix |= bcast[0] << (p * 8);
        remaining -= bcast[1];
        __syncthreads();
    }
    const unsigned T = prefix;
    const unsigned need = remaining;   // how many == T to take (ascending index)

    // each thread owns 8 consecutive positions
    const int p0 = tid * 8;
    unsigned vloc[8];
#pragma unroll
    for (int j = 0; j < 8; ++j) vloc[j] = vals[p0 + j];

    // pass 1: rank among equals (ascending index)
    unsigned eqpre[8]; unsigned myeq = 0;
#pragma unroll
    for (int j = 0; j < 8; ++j) { eqpre[j] = myeq; myeq += (vloc[j] == T) ? 1u : 0u; }
    // block exclusive scan of myeq
    unsigned inc = myeq;
#pragma unroll
    for (int o = 1; o < 64; o <<= 1) { unsigned u = __shfl_up(inc, o); if (lane >= o) inc += u; }
    if (lane == 63) wsum[wid] = inc;
    __syncthreads();
    if (wid == 0) {
        unsigned w = (lane < 16) ? wsum[lane] : 0u;
        unsigned winc = w;
#pragma unroll
        for (int o = 1; o < 16; o <<= 1) { unsigned u = __shfl_up(winc, o); if (lane >= o) winc += u; }
        if (lane < 16) wsum[lane] = winc - w;
    }
    __syncthreads();
    const unsigned eqbase = wsum[wid] + inc - myeq;
    __syncthreads();

    // pass 2: final selection flags + compaction offsets
    unsigned fpre[8]; unsigned myf = 0; unsigned fl = 0;
#pragma unroll
    for (int j = 0; j < 8; ++j) {
        bool f = (vloc[j] > T) || ((vloc[j] == T) && (eqbase + eqpre[j] < need));
        fl |= (f ? 1u : 0u) << j;
        fpre[j] = myf;
        myf += f ? 1u : 0u;
    }
    unsigned inc2 = myf;
#pragma unroll
    for (int o = 1; o < 64; o <<= 1) { unsigned u = __shfl_up(inc2, o); if (lane >= o) inc2 += u; }
    if (lane == 63) wsum[wid] = inc2;
    __syncthreads();
    if (wid == 0) {
        unsigned w = (lane < 16) ? wsum[lane] : 0u;
        unsigned winc = w;
#pragma unroll
        for (int o = 1; o < 16; o <<= 1) { unsigned u = __shfl_up(winc, o); if (lane >= o) winc += u; }
        if (lane < 16) wsum[lane] = winc - w;
    }
    __syncthreads();
    const unsigned fbase = wsum[wid] + inc2 - myf;
#pragma unroll
    for (int j = 0; j < 8; ++j)
        if ((fl >> j) & 1u)
            indices[b * KSEL + fbase + fpre[j]] = p0 + j;
}

// ------------------------------------------------------------- RoPE tables
__global__ void k_rope_tab(const int* __restrict__ idxs,
                           float* __restrict__ rcos, float* __restrict__ rsin) {
    int g = blockIdx.x * blockDim.x + threadIdx.x;
    if (g >= B_SZ * KSEL * 32) return;
    int i = g & 31, bm = g >> 5;
    int b = bm >> 10, m = bm & 1023;
    float pos = (float)idxs[b * KSEL + m];
    // theta_i = 10000^(-2i/64) computed in double, rounded to fp32, then fp32 multiply
    double th = exp2(-(double)i * (13.287712379549449 / 32.0));
    float freq = pos * (float)th;
    float s, c;
    sincosf(freq, &s, &c);
    rcos[g] = c;
    rsin[g] = s;
}

__global__ __launch_bounds__(256) void k_rope_apply(float* __restrict__ qkv,
                                                    const float* __restrict__ rcos,
                                                    const float* __restrict__ rsin) {
    int bm = blockIdx.x;
    float* row = qkv + (size_t)bm * 4096;
    for (int p = threadIdx.x; p < 1536; p += 256) {   // 3 streams x 16 heads x 32 pairs
        int s = p / 512, r = p % 512;
        int h = r >> 5, i = r & 31;
        float c = rcos[bm * 32 + i], sn = rsin[bm * 32 + i];
        int off = s * 1024 + h * 64 + 2 * i;
        float x1 = row[off], x2 = row[off + 1];
        row[off]     = x1 * c - x2 * sn;
        row[off + 1] = x1 * sn + x2 * c;
    }
}

// -------------------------------------------------------- QKV GEMM (gathered)
// qkv[r, n] = sum_k x[row(r), k] * Wq[n, k];  r in [0, B*K), n in [0, 4096)
__global__ __launch_bounds__(256) void k_qkv(const float* __restrict__ x,
                                             const float* __restrict__ Wq,
                                             const int* __restrict__ idxs,
                                             float* __restrict__ qkv) {
    __shared__ float As[16][128];
    __shared__ float Bs[16][128];
    __shared__ int rows[128];
    const int tid = threadIdx.x;
    const int bn = blockIdx.x, bm = blockIdx.y;
    if (tid < 128) {
        int r = bm * 128 + tid;
        int b = r >> 10, m = r & 1023;
        rows[tid] = b * S_LEN + idxs[b * KSEL + m];
    }
    const int tx = tid & 15, ty = tid >> 4;
    const int lm = tid >> 1, lk = (tid & 1) * 8;
    float acc[8][8];
#pragma unroll
    for (int i = 0; i < 8; ++i)
#pragma unroll
        for (int j = 0; j < 8; ++j) acc[i][j] = 0.f;
    __syncthreads();
    const size_t arow = (size_t)rows[lm] * DMODEL;
    const float* bbase = Wq + (size_t)(bn * 128 + lm) * DMODEL + lk;
    for (int k0 = 0; k0 < DMODEL; k0 += 16) {
        const float* asrc = x + arow + k0 + lk;
        float4 a0 = *(const float4*)asrc;
        float4 a1 = *(const float4*)(asrc + 4);
        float4 b0 = *(const float4*)(bbase + k0);
        float4 b1 = *(const float4*)(bbase + k0 + 4);
        __syncthreads();
        As[lk + 0][lm] = a0.x; As[lk + 1][lm] = a0.y; As[lk + 2][lm] = a0.z; As[lk + 3][lm] = a0.w;
        As[lk + 4][lm] = a1.x; As[lk + 5][lm] = a1.y; As[lk + 6][lm] = a1.z; As[lk + 7][lm] = a1.w;
        Bs[lk + 0][lm] = b0.x; Bs[lk + 1][lm] = b0.y; Bs[lk + 2][lm] = b0.z; Bs[lk + 3][lm] = b0.w;
        Bs[lk + 4][lm] = b1.x; Bs[lk + 5][lm] = b1.y; Bs[lk + 6][lm] = b1.z; Bs[lk + 7][lm] = b1.w;
        __syncthreads();
#pragma unroll
        for (int k = 0; k < 16; ++k) {
            float a[8], bb[8];
            *(float4*)&a[0]  = *(const float4*)&As[k][ty * 4];
            *(float4*)&a[4]  = *(const float4*)&As[k][64 + ty * 4];
            *(float4*)&bb[0] = *(const float4*)&Bs[k][tx * 4];
            *(float4*)&bb[4] = *(const float4*)&Bs[k][64 + tx * 4];
#pragma unroll
            for (int i = 0; i < 8; ++i)
#pragma unroll
                for (int j = 0; j < 8; ++j) acc[i][j] += a[i] * bb[j];
        }
    }
#pragma unroll
    for (int i = 0; i < 8; ++i) {
        int r = bm * 128 + ((i < 4) ? (ty * 4 + i) : (60 + ty * 4 + i));
        float* crow = qkv + (size_t)r * 4096 + bn * 128;
        *(float4*)&crow[tx * 4]      = make_float4(acc[i][0], acc[i][1], acc[i][2], acc[i][3]);
        *(float4*)&crow[64 + tx * 4] = make_float4(acc[i][4], acc[i][5], acc[i][6], acc[i][7]);
    }
}

// ------------------------------------------------------------- attention
// grid: 1024 = b(2) x h(16) x stream(2) x qtile(16); 256 threads;
// 4 lanes per query (dim-split by 16), 64 queries per block.
// Keys trimmed to [chunk_start-256, qtile_end): indices ascending => keys
// past the block's last query are always masked.
__global__ __launch_bounds__(256) void k_attn(const float* __restrict__ qkv,
                                              const int* __restrict__ idxs,
                                              float* __restrict__ o1,
                                              float* __restrict__ o2) {
    const int lin = blockIdx.x;
    const int qt = lin & 15;
    const int s  = (lin >> 4) & 1;
    const int h  = (lin >> 5) & 15;
    const int b  = lin >> 9;
    const int qbase = qt * 64;
    const int c = qt >> 2;
    const int k0 = (c >= 1) ? (c - 1) * 256 : 0;
    const int kend = qbase + 64;
    const int tid = threadIdx.x;
    const int qloc = tid >> 2, dp = tid & 3;

    __shared__ float Kt[64][68];
    __shared__ float Vt[64][68];
    __shared__ int pks[64];

    const int pq = idxs[b * KSEL + qbase + qloc];
    const float* qrow = qkv + ((size_t)(b * KSEL + qbase + qloc) * 4096)
                        + s * 1024 + h * 64 + dp * 16;
    float4 qv[4];
#pragma unroll
    for (int i = 0; i < 4; ++i) qv[i] = ((const float4*)qrow)[i];
    float4 accv[4];
#pragma unroll
    for (int i = 0; i < 4; ++i) accv[i] = make_float4(0.f, 0.f, 0.f, 0.f);
    float m = -INFINITY, l = 0.f;

    for (int kt = k0; kt < kend; kt += 64) {
        __syncthreads();
        {
            const int kk = tid >> 2;
            const size_t krow = (size_t)(b * KSEL + kt + kk) * 4096;
            const float4* ksrc = (const float4*)(qkv + krow + 2048 + h * 64 + dp * 16);
            const float4* vsrc = (const float4*)(qkv + krow + 3072 + h * 64 + dp * 16);
#pragma unroll
            for (int j = 0; j < 4; ++j) {
                *(float4*)&Kt[kk][dp * 16 + 4 * j] = ksrc[j];
                *(float4*)&Vt[kk][dp * 16 + 4 * j] = vsrc[j];
            }
            if (tid < 64) pks[tid] = idxs[b * KSEL + kt + tid];
        }
        __syncthreads();
#pragma unroll 4
        for (int j = 0; j < 64; ++j) {
            const float* kr = &Kt[j][dp * 16];
            float4 ka = *(const float4*)&kr[0];
            float4 kb = *(const float4*)&kr[4];
            float4 kc = *(const float4*)&kr[8];
            float4 kd = *(const float4*)&kr[12];
            float part = qv[0].x * ka.x + qv[0].y * ka.y + qv[0].z * ka.z + qv[0].w * ka.w
                       + qv[1].x * kb.x + qv[1].y * kb.y + qv[1].z * kb.z + qv[1].w * kb.w
                       + qv[2].x * kc.x + qv[2].y * kc.y + qv[2].z * kc.z + qv[2].w * kc.w
                       + qv[3].x * kd.x + qv[3].y * kd.y + qv[3].z * kd.z + qv[3].w * kd.w;
            part += __shfl_xor(part, 1);
            part += __shfl_xor(part, 2);
            float sc = part * 0.125f;
            int pkk = pks[j];
            bool ok = (pkk <= pq) && (pq - pkk < WINDOW);
            sc = ok ? sc : NEG_BIG;
            if (sc > m) {
                float sf = expf(m - sc);   // m may be -inf: expf(-inf)=0 zeroes history
                l *= sf;
#pragma unroll
                for (int i = 0; i < 4; ++i) {
                    accv[i].x *= sf; accv[i].y *= sf; accv[i].z *= sf; accv[i].w *= sf;
                }
                m = sc;
            }
            float p = expf(sc - m);
            l += p;
            const float* vr = &Vt[j][dp * 16];
            float4 va = *(const float4*)&vr[0];
            float4 vb = *(const float4*)&vr[4];
            float4 vc = *(const float4*)&vr[8];
            float4 vd = *(const float4*)&vr[12];
            accv[0].x += p * va.x; accv[0].y += p * va.y; accv[0].z += p * va.z; accv[0].w += p * va.w;
            accv[1].x += p * vb.x; accv[1].y += p * vb.y; accv[1].z += p * vb.z; accv[1].w += p * vb.w;
            accv[2].x += p * vc.x; accv[2].y += p * vc.y; accv[2].z += p * vc.z; accv[2].w += p * vc.w;
            accv[3].x += p * vd.x; accv[3].y += p * vd.y; accv[3].z += p * vd.z; accv[3].w += p * vd.w;
        }
    }
    const float inv = 1.0f / l;
    float* dst = (s ? o2 : o1) + ((size_t)(b * KSEL + qbase + qloc) * 1024) + h * 64 + dp * 16;
#pragma unroll
    for (int i = 0; i < 4; ++i) {
        float4 ov = accv[i];
        ((float4*)dst)[i] = make_float4(ov.x * inv, ov.y * inv, ov.z * inv, ov.w * inv);
    }
}

// ------------------------------------- diff + output GEMM: y = (o1 - lam*o2) @ Wo^T
__global__ __launch_bounds__(256) void k_ogemm(const float* __restrict__ o1,
                                               const float* __restrict__ o2,
                                               const float* __restrict__ Wo,
                                               const float* __restrict__ dll,
                                               float* __restrict__ y) {
    __shared__ float As[16][128];
    __shared__ float Bs[16][128];
    __shared__ float lams[16];
    const int tid = threadIdx.x;
    const int bn = blockIdx.x, bm = blockIdx.y;
    if (tid < 16) lams[tid] = 1.0f / (1.0f + expf(-dll[tid]));
    const int tx = tid & 15, ty = tid >> 4;
    const int lm = tid >> 1, lk = (tid & 1) * 8;
    float acc[8][8];
#pragma unroll
    for (int i = 0; i < 8; ++i)
#pragma unroll
        for (int j = 0; j < 8; ++j) acc[i][j] = 0.f;
    __syncthreads();
    const int r = bm * 128 + lm;
    const float* s1base = o1 + (size_t)r * 1024 + lk;
    const float* s2base = o2 + (size_t)r * 1024 + lk;
    const float* bbase = Wo + (size_t)(bn * 128 + lm) * 1024 + lk;
    for (int k0 = 0; k0 < 1024; k0 += 16) {
        float lam = lams[(k0 + lk) >> 6];
        float4 p0 = *(const float4*)(s1base + k0);
        float4 p1 = *(const float4*)(s1base + k0 + 4);
        float4 q0 = *(const float4*)(s2base + k0);
        float4 q1 = *(const float4*)(s2base + k0 + 4);
        float4 b0 = *(const float4*)(bbase + k0);
        float4 b1 = *(const float4*)(bbase + k0 + 4);
        __syncthreads();
        As[lk + 0][lm] = p0.x - lam * q0.x; As[lk + 1][lm] = p0.y - lam * q0.y;
        As[lk + 2][lm] = p0.z - lam * q0.z; As[lk + 3][lm] = p0.w - lam * q0.w;
        As[lk + 4][lm] = p1.x - lam * q1.x; As[lk + 5][lm] = p1.y - lam * q1.y;
        As[lk + 6][lm] = p1.z - lam * q1.z; As[lk + 7][lm] = p1.w - lam * q1.w;
        Bs[lk + 0][lm] = b0.x; Bs[lk + 1][lm] = b0.y; Bs[lk + 2][lm] = b0.z; Bs[lk + 3][lm] = b0.w;
        Bs[lk + 4][lm] = b1.x; Bs[lk + 5][lm] = b1.y; Bs[lk + 6][lm] = b1.z; Bs[lk + 7][lm] = b1.w;
        __syncthreads();
#pragma unroll
        for (int k = 0; k < 16; ++k) {
            float a[8], bb[8];
            *(float4*)&a[0]  = *(const float4*)&As[k][ty * 4];
            *(float4*)&a[4]  = *(const float4*)&As[k][64 + ty * 4];
            *(float4*)&bb[0] = *(const float4*)&Bs[k][tx * 4];
            *(float4*)&bb[4] = *(const float4*)&Bs[k][64 + tx * 4];
#pragma unroll
            for (int i = 0; i < 8; ++i)
#pragma unroll
                for (int j = 0; j < 8; ++j) acc[i][j] += a[i] * bb[j];
        }
    }
#pragma unroll
    for (int i = 0; i < 8; ++i) {
        int r2 = bm * 128 + ((i < 4) ? (ty * 4 + i) : (60 + ty * 4 + i));
        float* crow = y + (size_t)r2 * 1024 + bn * 128;
        *(float4*)&crow[tx * 4]      = make_float4(acc[i][0], acc[i][1], acc[i][2], acc[i][3]);
        *(float4*)&crow[64 + tx * 4] = make_float4(acc[i][4], acc[i][5], acc[i][6], acc[i][7]);
    }
}

// -------------------------------------------------- RMS norm + scatter rows
__global__ __launch_bounds__(256) void k_rms(const float* __restrict__ y,
                                             const int* __restrict__ idxs,
                                             const float* __restrict__ w,
                                             float* __restrict__ out) {
    const int r = blockIdx.x;
    const int b = r >> 10, m = r & 1023;
    const float4 v = ((const float4*)(y + (size_t)r * 1024))[threadIdx.x];
    double ss = (double)v.x * v.x + (double)v.y * v.y + (double)v.z * v.z + (double)v.w * v.w;
    int lane = threadIdx.x & 63, wid = threadIdx.x >> 6;
#pragma unroll
    for (int o = 32; o; o >>= 1) ss += __shfl_down(ss, o);
    __shared__ double wr[4];
    if (lane == 0) wr[wid] = ss;
    __syncthreads();
    double tot = wr[0] + wr[1] + wr[2] + wr[3];
    float sc = 1.0f / sqrtf((float)(tot * (1.0 / 1024.0)) + RMSEPS);
    float4 wv = ((const float4*)w)[threadIdx.x];
    int row = idxs[b * KSEL + m];
    float4 o4 = make_float4((v.x * sc) * wv.x, (v.y * sc) * wv.y,
                            (v.z * sc) * wv.z, (v.w * sc) * wv.w);
    ((float4*)(out + ((size_t)b * S_LEN + row) * 1024))[threadIdx.x] = o4;
}

// ----------------------------------------------------------------- launcher
extern "C" void kernel_launch(void* const* d_in, const int* in_sizes, int n_in,
                              void* d_out, int out_size, void* d_ws, size_t ws_size,
                              hipStream_t stream) {
    (void)in_sizes; (void)n_in; (void)out_size; (void)ws_size;
    const float* x     = (const float*)d_in[0];
    const float* cheby = (const float*)d_in[1];
    const float* Wqkv  = (const float*)d_in[2];
    const float* Wo    = (const float*)d_in[3];
    const float* rmsw  = (const float*)d_in[4];
    const float* dll   = (const float*)d_in[5];
    float* out = (float*)d_out;

    float* ws = (float*)d_ws;
    float* scores = ws;                                   // 16384
    int*   indices = (int*)(ws + 16384);                  // 2048 ints
    float* rcos = ws + 16384 + 2048;                      // 65536
    float* rsin = rcos + 65536;                           // 65536
    float* qkv  = rsin + 65536;                           // 8388608 (B*K*4096)
    float* o1   = qkv + 8388608;                          // 2097152
    float* o2   = o1 + 2097152;                           // 2097152
    float* yb   = o2 + 2097152;                           // 2097152
    // total ~59.3 MB of workspace

    k_zero<<<16384, 256, 0, stream>>>((float4*)out, (B_SZ * S_LEN * DMODEL) / 4);
    k_scores<<<B_SZ * (S_LEN - 1), 256, 0, stream>>>(x, cheby, scores);
    k_topk<<<B_SZ, 1024, 0, stream>>>(scores, indices);
    k_rope_tab<<<(B_SZ * KSEL * 32 + 255) / 256, 256, 0, stream>>>(indices, rcos, rsin);
    k_qkv<<<dim3(32, 16), 256, 0, stream>>>(x, Wqkv, indices, qkv);
    k_rope_apply<<<B_SZ * KSEL, 256, 0, stream>>>(qkv, rcos, rsin);
    k_attn<<<1024, 256, 0, stream>>>(qkv, indices, o1, o2);
    k_ogemm<<<dim3(8, 16), 256, 0, stream>>>(o1, o2, Wo, dll, yb);
    k_rms<<<B_SZ * KSEL, 256, 0, stream>>>(yb, indices, rmsw, out);
}